// Round 5
// baseline (867.198 us; speedup 1.0000x reference)
//
#include <hip/hip_runtime.h>
#include <stdint.h>

typedef short short8 __attribute__((ext_vector_type(8)));
typedef float floatx4 __attribute__((ext_vector_type(4)));

#define BK 256  // nodes per bucket (== k_fine block size)

static __device__ __forceinline__ float bflo(unsigned int u) {
    union { unsigned int i; float f; } v; v.i = u << 16; return v.f;
}
static __device__ __forceinline__ float bfhi(unsigned int u) {
    union { unsigned int i; float f; } v; v.i = u & 0xffff0000u; return v.f;
}
static __device__ __forceinline__ unsigned short f2bf(float f) {
    union { float f; unsigned int i; } v; v.f = f;
    unsigned int u = v.i;
    unsigned int r = u + 0x7fffu + ((u >> 16) & 1u);
    return (unsigned short)(r >> 16);
}

// ---------------- CSR build: two-level counting sort by dst ----------------

__global__ void k_zero_cnt(int* bucket_cnt, int K) {
    int i = blockIdx.x * 256 + threadIdx.x;
    if (i < K) bucket_cnt[i] = 0;
}

__global__ __launch_bounds__(256) void k_hist(const int* __restrict__ dst, int* bucket_cnt,
                                              int E, int N, int K) {
    __shared__ int h[512];
    int t = threadIdx.x;
    for (int i = t; i < K; i += 256) h[i] = 0;
    __syncthreads();
    int per = (E + gridDim.x - 1) / gridDim.x;
    int lo = blockIdx.x * per, hi = min(lo + per, E);
    for (int e = lo + t; e < hi; e += 256) {
        unsigned int d = (unsigned int)dst[e];
        if (d < (unsigned int)N) atomicAdd(&h[d >> 8], 1);
    }
    __syncthreads();
    for (int i = t; i < K; i += 256) if (h[i]) atomicAdd(&bucket_cnt[i], h[i]);
}

__global__ void k_scanK(const int* __restrict__ bucket_cnt, int* bucket_off, int* bucket_cur,
                        int* row_start, int K, int N) {
    __shared__ int s[512];
    int t = threadIdx.x;
    int v = (t < K) ? bucket_cnt[t] : 0;
    s[t] = v; __syncthreads();
    for (int off = 1; off < 512; off <<= 1) {
        int x = (t >= off) ? s[t - off] : 0;
        __syncthreads();
        s[t] += x;
        __syncthreads();
    }
    if (t < K) { bucket_off[t] = s[t] - v; bucket_cur[t] = s[t] - v; }
    if (t == K - 1) { bucket_off[K] = s[t]; row_start[N] = s[t]; }
}

__global__ __launch_bounds__(256) void k_binscatter(const int* __restrict__ src,
                                                    const int* __restrict__ dst,
                                                    int* bucket_cur, uint2* __restrict__ tmp,
                                                    int E, int N, int K) {
    __shared__ int h[512];
    __shared__ int base[512];
    int t = threadIdx.x;
    for (int i = t; i < K; i += 256) h[i] = 0;
    __syncthreads();
    int per = (E + gridDim.x - 1) / gridDim.x;
    int lo = blockIdx.x * per, hi = min(lo + per, E);
    for (int e = lo + t; e < hi; e += 256) {
        unsigned int d = (unsigned int)dst[e], sv = (unsigned int)src[e];
        if (d < (unsigned int)N && sv < (unsigned int)N) atomicAdd(&h[d >> 8], 1);
    }
    __syncthreads();
    for (int i = t; i < K; i += 256) {
        int c = h[i];
        base[i] = c ? atomicAdd(&bucket_cur[i], c) : 0;
        h[i] = 0;
    }
    __syncthreads();
    for (int e = lo + t; e < hi; e += 256) {
        unsigned int d = (unsigned int)dst[e], sv = (unsigned int)src[e];
        if (d < (unsigned int)N && sv < (unsigned int)N) {
            int k = d >> 8;
            int p = base[k] + atomicAdd(&h[k], 1);
            tmp[p] = make_uint2(sv, d);
        }
    }
}

__global__ __launch_bounds__(256) void k_fine(const uint2* __restrict__ tmp,
                                              const int* __restrict__ bucket_off,
                                              int* __restrict__ row_start, float* __restrict__ dinv,
                                              int* __restrict__ csr, int N) {
    __shared__ int deg[BK];
    __shared__ int scn[BK];
    __shared__ int cur[BK];
    int b = blockIdx.x;
    int t = threadIdx.x;
    int lo = bucket_off[b], hi = bucket_off[b + 1];
    deg[t] = 0;
    __syncthreads();
    for (int e = lo + t; e < hi; e += 256) {
        int d = tmp[e].y & (BK - 1);
        atomicAdd(&deg[d], 1);
    }
    __syncthreads();
    int v = deg[t];
    scn[t] = v; __syncthreads();
    for (int off = 1; off < 256; off <<= 1) {
        int x = (t >= off) ? scn[t - off] : 0;
        __syncthreads();
        scn[t] += x;
        __syncthreads();
    }
    int rs = lo + scn[t] - v;
    cur[t] = rs;
    int node = b * BK + t;
    if (node < N) { row_start[node] = rs; dinv[node] = rsqrtf((float)(v + 1)); }
    __syncthreads();
    for (int e = lo + t; e < hi; e += 256) {
        uint2 ed = tmp[e];
        int d = ed.y & (BK - 1);
        int p = atomicAdd(&cur[d], 1);
        csr[p] = (int)ed.x;
    }
}

// ---------------- W pre-convert: fp32 [K][Nc] -> bf16 transposed [Nc][K] ----------------

__global__ void k_wconv(const float* __restrict__ W, unsigned short* __restrict__ Wt,
                        int K, int Nc) {
    int i = blockIdx.x * 256 + threadIdx.x;
    if (i < K * Nc) {
        int k = i / Nc, n = i % Nc;
        Wt[n * K + k] = f2bf(W[i]);
    }
}

// ---------------- GEMM: out[M,NOUT] = X[M,128] @ W[128,NOUT], K=128 ----------------
// Wbf: bf16 pre-transposed [NOUT][128]. X: fp32 row-major (XF32) or bf16 sliced [8][N][16]
// (ASLICED). Out: bf16 sliced (OSLICED) or fp32 row-major.
// Persistent blocks: W staged once, multiple row-tiles per block.

template <int NOUT, bool SCALE, bool BIAS, bool XF32, bool ASLICED, bool OSLICED>
__global__ __launch_bounds__(256, 2) void k_gemm(
    const void* __restrict__ Xv, const unsigned short* __restrict__ Wbf,
    const float* __restrict__ bias, const float* __restrict__ dinv,
    void* __restrict__ outv, int M, int MB) {
    __shared__ __align__(16) unsigned short Wl[NOUT * 136];
    int t = threadIdx.x;
    for (int c = t; c < NOUT * 16; c += 256) {
        short8 v = *(const short8*)(Wbf + (size_t)c * 8);
        *(short8*)(&Wl[(c >> 4) * 136 + (c & 15) * 8]) = v;
    }
    __syncthreads();

    int wave = t >> 6, lane = t & 63;
    int quad = lane >> 4, l16 = lane & 15;
    constexpr int NT = NOUT / 16;

    for (int mb = blockIdx.x; mb < MB; mb += gridDim.x) {
        int m0 = mb * 64 + wave * 16;
        int mr = m0 + l16;
        int mrc = mr < M ? mr : M - 1;

        floatx4 acc[NT];
#pragma unroll
        for (int i = 0; i < NT; i++) acc[i] = (floatx4){0.f, 0.f, 0.f, 0.f};

#pragma unroll
        for (int kc = 0; kc < 4; kc++) {
            short8 a;
            if (XF32) {
                const float* X = (const float*)Xv;
                const float* p = X + (size_t)mrc * 128 + kc * 32 + quad * 8;
                float4 xa = *(const float4*)p;
                float4 xb = *(const float4*)(p + 4);
                a[0] = (short)f2bf(xa.x); a[1] = (short)f2bf(xa.y);
                a[2] = (short)f2bf(xa.z); a[3] = (short)f2bf(xa.w);
                a[4] = (short)f2bf(xb.x); a[5] = (short)f2bf(xb.y);
                a[6] = (short)f2bf(xb.z); a[7] = (short)f2bf(xb.w);
            } else if (ASLICED) {
                const unsigned short* X = (const unsigned short*)Xv;
                int slice = kc * 2 + (quad >> 1);
                a = *(const short8*)(X + ((size_t)slice * M + mrc) * 16 + (quad & 1) * 8);
            } else {
                const unsigned short* X = (const unsigned short*)Xv;
                a = *(const short8*)(X + (size_t)mrc * 128 + kc * 32 + quad * 8);
            }
#pragma unroll
            for (int nt = 0; nt < NT; nt++) {
                short8 b = *(const short8*)(&Wl[(nt * 16 + l16) * 136 + kc * 32 + quad * 8]);
                acc[nt] = __builtin_amdgcn_mfma_f32_16x16x32_bf16(a, b, acc[nt], 0, 0, 0);
            }
        }

        // C layout: col = l16, row (within 16) = quad*4 + i
#pragma unroll
        for (int i = 0; i < 4; i++) {
            int r = m0 + quad * 4 + i;
            if (r >= M) continue;
            float sc = SCALE ? dinv[r] : 1.0f;
#pragma unroll
            for (int nt = 0; nt < NT; nt++) {
                int n = nt * 16 + l16;
                float v = acc[nt][i] * sc;
                if (BIAS) v += bias[n];
                if (OSLICED) {
                    // sliced bf16: [slice=nt][node=r][ch=l16]
                    ((unsigned short*)outv)[((size_t)nt * M + r) * 16 + l16] = f2bf(v);
                } else {
                    ((float*)outv)[(size_t)r * NOUT + n] = v;
                }
            }
        }
    }
}

// ---------------- Sliced aggregation ----------------
// At[s][d][16] = relu(dinv[d]*(Hst[s][d] + sum_nbr Hst[s][src]) + b[s*16..])
// slice = blockIdx & 7 -> XCD-affine via round-robin dispatch; slice table 3.2MB fits 4MB L2.
// lane = eg(8 edges in flight) * 8 + cp(channel pair); shfl_xor reduce over eg.

__global__ __launch_bounds__(256, 8) void k_agg_sliced(
    const unsigned short* __restrict__ Hst, const int* __restrict__ csr,
    const int* __restrict__ row_start, const float* __restrict__ dinv,
    const float* __restrict__ bias, unsigned short* __restrict__ At, int N) {
    int b = blockIdx.x;
    int s = b & 7;
    int nb = b >> 3;
    int wave = threadIdx.x >> 6, lane = threadIdx.x & 63;
    int eg = lane >> 3, cp = lane & 7;
    int Nm1 = N - 1;
    const unsigned short* Ts = Hst + (size_t)s * N * 16;
    unsigned short* As = At + (size_t)s * N * 16;
    float bs0 = bias[s * 16 + cp * 2];
    float bs1 = bias[s * 16 + cp * 2 + 1];

    int node0 = nb * 64 + wave * 16;
#pragma unroll 1
    for (int ni = 0; ni < 16; ni++) {
        int node = node0 + ni;
        if (node >= N) break;
        int start = row_start[node];
        int end = row_start[node + 1];
        float a0 = 0.f, a1 = 0.f;
        int G = (end - start + 7) >> 3;
        int e = start + eg;
        for (int g = 0; g < G; g++, e += 8) {
            int ec = e < end ? e : end - 1;
            int id = __builtin_nontemporal_load(csr + ec);
            id = min(max(id, 0), Nm1);
            unsigned int u = *(const unsigned int*)(Ts + (size_t)id * 16 + cp * 2);
            if (e < end) { a0 += bflo(u); a1 += bfhi(u); }
        }
#pragma unroll
        for (int off = 8; off < 64; off <<= 1) {
            a0 += __shfl_xor(a0, off);
            a1 += __shfl_xor(a1, off);
        }
        unsigned int su = *(const unsigned int*)(Ts + (size_t)node * 16 + cp * 2);
        a0 += bflo(su);
        a1 += bfhi(su);
        float di = dinv[node];
        float r0 = fmaxf(fmaf(di, a0, bs0), 0.f);
        float r1 = fmaxf(fmaf(di, a1, bs1), 0.f);
        if (eg == 0) {
            unsigned int pk = (unsigned int)f2bf(r0) | ((unsigned int)f2bf(r1) << 16);
            __builtin_nontemporal_store(pk, (unsigned int*)(As + (size_t)node * 16 + cp * 2));
        }
    }
}

// ---------------- launch ----------------

extern "C" void kernel_launch(void* const* d_in, const int* in_sizes, int n_in,
                              void* d_out, int out_size, void* d_ws, size_t ws_size,
                              hipStream_t stream) {
    const float* x  = (const float*)d_in[0];
    const int* ei   = (const int*)d_in[1];
    const float* W1 = (const float*)d_in[2];
    const float* b1 = (const float*)d_in[3];
    const float* W2 = (const float*)d_in[4];
    const float* b2 = (const float*)d_in[5];
    const float* Wf = (const float*)d_in[6];
    const float* bf = (const float*)d_in[7];

    int N = in_sizes[0] / 128;
    int E = in_sizes[1] / 2;
    const int* src = ei;
    const int* dst = ei + E;
    int K = (N + BK - 1) / BK;

    size_t need = 0;
    auto pad = [](size_t b) { return (b + 255) & ~(size_t)255; };
    size_t o_bcnt = need; need += pad(512 * 4);
    size_t o_boff = need; need += pad(513 * 4);
    size_t o_bcur = need; need += pad(512 * 4);
    size_t o_rs   = need; need += pad(((size_t)N + 1) * 4);
    size_t o_dinv = need; need += pad((size_t)N * 4);
    size_t o_wbf  = need; need += pad((16384 + 16384 + 8192) * 2);
    size_t o_csr  = need; need += pad((size_t)E * 4);
    size_t o_hs   = need; need += pad((size_t)N * 128 * 2);
    size_t o_a    = need; need += pad((size_t)N * 128 * 2);
    if (ws_size < need) return;
    if ((size_t)E * 8 > (size_t)N * 128 * 2) return;  // tmp must fit in A alias

    char* ws = (char*)d_ws;
    int* bucket_cnt = (int*)(ws + o_bcnt);
    int* bucket_off = (int*)(ws + o_boff);
    int* bucket_cur = (int*)(ws + o_bcur);
    int* row_start  = (int*)(ws + o_rs);
    float* dinv     = (float*)(ws + o_dinv);
    unsigned short* wb1 = (unsigned short*)(ws + o_wbf);
    unsigned short* wb2 = wb1 + 16384;
    unsigned short* wbf = wb2 + 16384;
    int* csr        = (int*)(ws + o_csr);
    unsigned short* Hst = (unsigned short*)(ws + o_hs);
    unsigned short* At  = (unsigned short*)(ws + o_a);
    uint2* tmp      = (uint2*)At;  // alias: tmp dead before At's first write

    // W pre-convert (independent of CSR build)
    k_wconv<<<64, 256, 0, stream>>>(W1, wb1, 128, 128);
    k_wconv<<<64, 256, 0, stream>>>(W2, wb2, 128, 128);
    k_wconv<<<32, 256, 0, stream>>>(Wf, wbf, 128, 64);

    // CSR build
    k_zero_cnt<<<(K + 255) / 256, 256, 0, stream>>>(bucket_cnt, K);
    k_hist<<<256, 256, 0, stream>>>(dst, bucket_cnt, E, N, K);
    k_scanK<<<1, 512, 0, stream>>>(bucket_cnt, bucket_off, bucket_cur, row_start, K, N);
    k_binscatter<<<256, 256, 0, stream>>>(src, dst, bucket_cur, tmp, E, N, K);
    k_fine<<<K, 256, 0, stream>>>(tmp, bucket_off, row_start, dinv, csr, N);

    int MB = (N + 63) / 64;
    int GG = (MB + 1) / 2;  // persistent: 2 row-tiles per block
    int GA = 8 * ((N + 63) / 64);

    k_gemm<128, true, false, true, false, true><<<GG, 256, 0, stream>>>(x, wb1, nullptr, dinv, Hst, N, MB);
    k_agg_sliced<<<GA, 256, 0, stream>>>(Hst, csr, row_start, dinv, b1, At, N);
    k_gemm<128, true, false, false, true, true><<<GG, 256, 0, stream>>>(At, wb2, nullptr, dinv, Hst, N, MB);
    k_agg_sliced<<<GA, 256, 0, stream>>>(Hst, csr, row_start, dinv, b2, At, N);
    k_gemm<64, false, true, false, true, false><<<GG, 256, 0, stream>>>(At, wbf, bf, nullptr, d_out, N, MB);
}

// Round 6
// 376.100 us; speedup vs baseline: 2.3058x; 2.3058x over previous
//
#include <hip/hip_runtime.h>
#include <stdint.h>

typedef short short8 __attribute__((ext_vector_type(8)));
typedef float floatx4 __attribute__((ext_vector_type(4)));

#define BK 256  // nodes per bucket (== k_fine block size)

static __device__ __forceinline__ float bflo(unsigned int u) {
    union { unsigned int i; float f; } v; v.i = u << 16; return v.f;
}
static __device__ __forceinline__ float bfhi(unsigned int u) {
    union { unsigned int i; float f; } v; v.i = u & 0xffff0000u; return v.f;
}
static __device__ __forceinline__ unsigned short f2bf(float f) {
    union { float f; unsigned int i; } v; v.f = f;
    unsigned int u = v.i;
    unsigned int r = u + 0x7fffu + ((u >> 16) & 1u);
    return (unsigned short)(r >> 16);
}

// ---------------- CSR build: two-level counting sort by dst ----------------

__global__ void k_zero_cnt(int* bucket_cnt, int K) {
    int i = blockIdx.x * 256 + threadIdx.x;
    if (i < K) bucket_cnt[i] = 0;
}

__global__ __launch_bounds__(256) void k_hist(const int* __restrict__ dst, int* bucket_cnt,
                                              int E, int N, int K) {
    __shared__ int h[512];
    int t = threadIdx.x;
    for (int i = t; i < K; i += 256) h[i] = 0;
    __syncthreads();
    int per = (E + gridDim.x - 1) / gridDim.x;
    int lo = blockIdx.x * per, hi = min(lo + per, E);
    for (int e = lo + t; e < hi; e += 256) {
        unsigned int d = (unsigned int)dst[e];
        if (d < (unsigned int)N) atomicAdd(&h[d >> 8], 1);
    }
    __syncthreads();
    for (int i = t; i < K; i += 256) if (h[i]) atomicAdd(&bucket_cnt[i], h[i]);
}

__global__ void k_scanK(const int* __restrict__ bucket_cnt, int* bucket_off, int* bucket_cur,
                        int* row_start, int K, int N) {
    __shared__ int s[512];
    int t = threadIdx.x;
    int v = (t < K) ? bucket_cnt[t] : 0;
    s[t] = v; __syncthreads();
    for (int off = 1; off < 512; off <<= 1) {
        int x = (t >= off) ? s[t - off] : 0;
        __syncthreads();
        s[t] += x;
        __syncthreads();
    }
    if (t < K) { bucket_off[t] = s[t] - v; bucket_cur[t] = s[t] - v; }
    if (t == K - 1) { bucket_off[K] = s[t]; row_start[N] = s[t]; }
}

__global__ __launch_bounds__(256) void k_binscatter(const int* __restrict__ src,
                                                    const int* __restrict__ dst,
                                                    int* bucket_cur, uint2* __restrict__ tmp,
                                                    int E, int N, int K) {
    __shared__ int h[512];
    __shared__ int base[512];
    int t = threadIdx.x;
    for (int i = t; i < K; i += 256) h[i] = 0;
    __syncthreads();
    int per = (E + gridDim.x - 1) / gridDim.x;
    int lo = blockIdx.x * per, hi = min(lo + per, E);
    for (int e = lo + t; e < hi; e += 256) {
        unsigned int d = (unsigned int)dst[e], sv = (unsigned int)src[e];
        if (d < (unsigned int)N && sv < (unsigned int)N) atomicAdd(&h[d >> 8], 1);
    }
    __syncthreads();
    for (int i = t; i < K; i += 256) {
        int c = h[i];
        base[i] = c ? atomicAdd(&bucket_cur[i], c) : 0;
        h[i] = 0;
    }
    __syncthreads();
    for (int e = lo + t; e < hi; e += 256) {
        unsigned int d = (unsigned int)dst[e], sv = (unsigned int)src[e];
        if (d < (unsigned int)N && sv < (unsigned int)N) {
            int k = d >> 8;
            int p = base[k] + atomicAdd(&h[k], 1);
            tmp[p] = make_uint2(sv, d);
        }
    }
}

__global__ __launch_bounds__(256) void k_fine(const uint2* __restrict__ tmp,
                                              const int* __restrict__ bucket_off,
                                              int* __restrict__ row_start, float* __restrict__ dinv,
                                              int* __restrict__ csr, int N) {
    __shared__ int deg[BK];
    __shared__ int scn[BK];
    __shared__ int cur[BK];
    int b = blockIdx.x;
    int t = threadIdx.x;
    int lo = bucket_off[b], hi = bucket_off[b + 1];
    deg[t] = 0;
    __syncthreads();
    for (int e = lo + t; e < hi; e += 256) {
        int d = tmp[e].y & (BK - 1);
        atomicAdd(&deg[d], 1);
    }
    __syncthreads();
    int v = deg[t];
    scn[t] = v; __syncthreads();
    for (int off = 1; off < 256; off <<= 1) {
        int x = (t >= off) ? scn[t - off] : 0;
        __syncthreads();
        scn[t] += x;
        __syncthreads();
    }
    int rs = lo + scn[t] - v;
    cur[t] = rs;
    int node = b * BK + t;
    if (node < N) { row_start[node] = rs; dinv[node] = rsqrtf((float)(v + 1)); }
    __syncthreads();
    for (int e = lo + t; e < hi; e += 256) {
        uint2 ed = tmp[e];
        int d = ed.y & (BK - 1);
        int p = atomicAdd(&cur[d], 1);
        csr[p] = (int)ed.x;
    }
}

// ---------------- W pre-convert: fp32 [K][Nc] -> bf16 transposed [Nc][K] ----------------

__global__ void k_wconv(const float* __restrict__ W, unsigned short* __restrict__ Wt,
                        int K, int Nc) {
    int i = blockIdx.x * 256 + threadIdx.x;
    if (i < K * Nc) {
        int k = i / Nc, n = i % Nc;
        Wt[n * K + k] = f2bf(W[i]);
    }
}

// ---------------- GEMM: out[M,NOUT] = X[M,128] @ W[128,NOUT], K=128 ----------------
// Wbf: bf16 pre-transposed [NOUT][128]. X: fp32 row-major (XF32) or bf16 row-major.
// Out: bf16 row-major or fp32 row-major (OUTF32). Persistent blocks: W staged once.

template <int NOUT, bool SCALE, bool BIAS, bool XF32, bool OUTF32>
__global__ __launch_bounds__(256, 2) void k_gemm(
    const void* __restrict__ Xv, const unsigned short* __restrict__ Wbf,
    const float* __restrict__ bias, const float* __restrict__ dinv,
    void* __restrict__ outv, int M, int MB) {
    // Wl[n*136 + k], stride 136 (272B ≡ 4 banks mod 32 -> 2-way conflict = free)
    __shared__ __align__(16) unsigned short Wl[NOUT * 136];
    int t = threadIdx.x;
    for (int c = t; c < NOUT * 16; c += 256) {
        short8 v = *(const short8*)(Wbf + (size_t)c * 8);
        *(short8*)(&Wl[(c >> 4) * 136 + (c & 15) * 8]) = v;
    }
    __syncthreads();

    int wave = t >> 6, lane = t & 63;
    int quad = lane >> 4, l16 = lane & 15;
    constexpr int NT = NOUT / 16;

    for (int mb = blockIdx.x; mb < MB; mb += gridDim.x) {
        int m0 = mb * 64 + wave * 16;
        int mr = m0 + l16;
        int mrc = mr < M ? mr : M - 1;

        floatx4 acc[NT];
#pragma unroll
        for (int i = 0; i < NT; i++) acc[i] = (floatx4){0.f, 0.f, 0.f, 0.f};

#pragma unroll
        for (int kc = 0; kc < 4; kc++) {
            short8 a;
            if (XF32) {
                const float* X = (const float*)Xv;
                const float* p = X + (size_t)mrc * 128 + kc * 32 + quad * 8;
                float4 xa = *(const float4*)p;
                float4 xb = *(const float4*)(p + 4);
                a[0] = (short)f2bf(xa.x); a[1] = (short)f2bf(xa.y);
                a[2] = (short)f2bf(xa.z); a[3] = (short)f2bf(xa.w);
                a[4] = (short)f2bf(xb.x); a[5] = (short)f2bf(xb.y);
                a[6] = (short)f2bf(xb.z); a[7] = (short)f2bf(xb.w);
            } else {
                const unsigned short* X = (const unsigned short*)Xv;
                a = *(const short8*)(X + (size_t)mrc * 128 + kc * 32 + quad * 8);
            }
#pragma unroll
            for (int nt = 0; nt < NT; nt++) {
                short8 b = *(const short8*)(&Wl[(nt * 16 + l16) * 136 + kc * 32 + quad * 8]);
                acc[nt] = __builtin_amdgcn_mfma_f32_16x16x32_bf16(a, b, acc[nt], 0, 0, 0);
            }
        }

        // C layout: col = l16, row (within 16) = quad*4 + i
#pragma unroll
        for (int i = 0; i < 4; i++) {
            int r = m0 + quad * 4 + i;
            if (r >= M) continue;
            float sc = SCALE ? dinv[r] : 1.0f;
#pragma unroll
            for (int nt = 0; nt < NT; nt++) {
                int n = nt * 16 + l16;
                float v = acc[nt][i] * sc;
                if (BIAS) v += bias[n];
                if (OUTF32) {
                    ((float*)outv)[(size_t)r * NOUT + n] = v;
                } else {
                    ((unsigned short*)outv)[(size_t)r * NOUT + n] = f2bf(v);
                }
            }
        }
    }
}

// ---------------- Aggregation ----------------
// out[d] = relu(dinv[d]*(Hs[d] + sum_nbr Hs[src]) + b); one wave/node, 2 ch/lane;
// unroll-8: 8 independent 256B row-gathers in flight per wave (MLP).

__global__ __launch_bounds__(256, 8) void k_aggregate(
    const unsigned short* __restrict__ Hs, const int* __restrict__ csr,
    const int* __restrict__ row_start,
    const float* __restrict__ dinv, const float* __restrict__ bias,
    unsigned short* __restrict__ out, int N, int E) {
    int wave = threadIdx.x >> 6, lane = threadIdx.x & 63;
    int node = blockIdx.x * 4 + wave;
    if (node >= N) return;
    int ch = lane * 2;
    int Nm1 = N - 1;

    unsigned int u = *(const unsigned int*)(Hs + (size_t)node * 128 + ch);
    float a0 = bflo(u), a1 = bfhi(u);

    int e = row_start[node];
    int end = row_start[node + 1];
    if (e < 0) e = 0;
    if (end > E) end = E;

    for (; e + 8 <= end; e += 8) {
        int idx[8];
#pragma unroll
        for (int j = 0; j < 8; j++) idx[j] = __builtin_nontemporal_load(csr + e + j);
        unsigned int uu[8];
#pragma unroll
        for (int j = 0; j < 8; j++) {
            int s = min(max(idx[j], 0), Nm1);
            uu[j] = *(const unsigned int*)(Hs + (size_t)s * 128 + ch);
        }
#pragma unroll
        for (int j = 0; j < 8; j++) { a0 += bflo(uu[j]); a1 += bfhi(uu[j]); }
    }
    if (e + 4 <= end) {
        int idx[4];
#pragma unroll
        for (int j = 0; j < 4; j++) idx[j] = __builtin_nontemporal_load(csr + e + j);
        unsigned int uu[4];
#pragma unroll
        for (int j = 0; j < 4; j++) {
            int s = min(max(idx[j], 0), Nm1);
            uu[j] = *(const unsigned int*)(Hs + (size_t)s * 128 + ch);
        }
#pragma unroll
        for (int j = 0; j < 4; j++) { a0 += bflo(uu[j]); a1 += bfhi(uu[j]); }
        e += 4;
    }
    for (; e < end; e++) {
        int s = min(max(__builtin_nontemporal_load(csr + e), 0), Nm1);
        unsigned int u0 = *(const unsigned int*)(Hs + (size_t)s * 128 + ch);
        a0 += bflo(u0);
        a1 += bfhi(u0);
    }

    float di = dinv[node];
    float r0 = fmaxf(fmaf(di, a0, bias[ch]), 0.f);
    float r1 = fmaxf(fmaf(di, a1, bias[ch + 1]), 0.f);
    unsigned int pk = (unsigned int)f2bf(r0) | ((unsigned int)f2bf(r1) << 16);
    __builtin_nontemporal_store(pk, (unsigned int*)(out + (size_t)node * 128 + ch));
}

// ---------------- launch ----------------

extern "C" void kernel_launch(void* const* d_in, const int* in_sizes, int n_in,
                              void* d_out, int out_size, void* d_ws, size_t ws_size,
                              hipStream_t stream) {
    const float* x  = (const float*)d_in[0];
    const int* ei   = (const int*)d_in[1];
    const float* W1 = (const float*)d_in[2];
    const float* b1 = (const float*)d_in[3];
    const float* W2 = (const float*)d_in[4];
    const float* b2 = (const float*)d_in[5];
    const float* Wf = (const float*)d_in[6];
    const float* bf = (const float*)d_in[7];

    int N = in_sizes[0] / 128;
    int E = in_sizes[1] / 2;
    const int* src = ei;
    const int* dst = ei + E;
    int K = (N + BK - 1) / BK;

    size_t need = 0;
    auto pad = [](size_t b) { return (b + 255) & ~(size_t)255; };
    size_t o_bcnt = need; need += pad(512 * 4);
    size_t o_boff = need; need += pad(513 * 4);
    size_t o_bcur = need; need += pad(512 * 4);
    size_t o_rs   = need; need += pad(((size_t)N + 1) * 4);
    size_t o_dinv = need; need += pad((size_t)N * 4);
    size_t o_wbf  = need; need += pad((16384 + 16384 + 8192) * 2);
    size_t o_csr  = need; need += pad((size_t)E * 4);
    size_t o_hs   = need; need += pad((size_t)N * 128 * 2);
    size_t o_a    = need; need += pad((size_t)N * 128 * 2);
    if (ws_size < need) return;
    if ((size_t)E * 8 > (size_t)N * 128 * 2) return;  // tmp must fit in A alias

    char* ws = (char*)d_ws;
    int* bucket_cnt = (int*)(ws + o_bcnt);
    int* bucket_off = (int*)(ws + o_boff);
    int* bucket_cur = (int*)(ws + o_bcur);
    int* row_start  = (int*)(ws + o_rs);
    float* dinv     = (float*)(ws + o_dinv);
    unsigned short* wb1 = (unsigned short*)(ws + o_wbf);
    unsigned short* wb2 = wb1 + 16384;
    unsigned short* wbf = wb2 + 16384;
    int* csr        = (int*)(ws + o_csr);
    unsigned short* Hs = (unsigned short*)(ws + o_hs);
    unsigned short* A  = (unsigned short*)(ws + o_a);
    uint2* tmp      = (uint2*)A;  // alias: tmp dead before A's first write

    // W pre-convert (tiny)
    k_wconv<<<64, 256, 0, stream>>>(W1, wb1, 128, 128);
    k_wconv<<<64, 256, 0, stream>>>(W2, wb2, 128, 128);
    k_wconv<<<32, 256, 0, stream>>>(Wf, wbf, 128, 64);

    // CSR build
    k_zero_cnt<<<(K + 255) / 256, 256, 0, stream>>>(bucket_cnt, K);
    k_hist<<<256, 256, 0, stream>>>(dst, bucket_cnt, E, N, K);
    k_scanK<<<1, 512, 0, stream>>>(bucket_cnt, bucket_off, bucket_cur, row_start, K, N);
    k_binscatter<<<256, 256, 0, stream>>>(src, dst, bucket_cur, tmp, E, N, K);
    k_fine<<<K, 256, 0, stream>>>(tmp, bucket_off, row_start, dinv, csr, N);

    int MB = (N + 63) / 64;
    int GG = (MB + 1) / 2;  // persistent: 2 row-tiles per block

    k_gemm<128, true, false, true, false><<<GG, 256, 0, stream>>>(x, wb1, nullptr, dinv, Hs, N, MB);
    k_aggregate<<<(N + 3) / 4, 256, 0, stream>>>(Hs, csr, row_start, dinv, b1, A, N, E);
    k_gemm<128, true, false, false, false><<<GG, 256, 0, stream>>>(A, wb2, nullptr, dinv, Hs, N, MB);
    k_aggregate<<<(N + 3) / 4, 256, 0, stream>>>(Hs, csr, row_start, dinv, b2, A, N, E);
    k_gemm<64, false, true, false, true><<<GG, 256, 0, stream>>>(A, wbf, bf, nullptr, d_out, N, MB);
}